// Round 2
// baseline (176.882 us; speedup 1.0000x reference)
//
#include <hip/hip_runtime.h>

#define S_DIM 4096
#define C_IN  256
#define E_DIM 512
#define HD    64
#define EPSV  1e-5f

typedef __attribute__((ext_vector_type(8))) short s8v;
typedef __attribute__((ext_vector_type(4))) short s4v;
typedef __attribute__((ext_vector_type(4))) float f4v;

__device__ __forceinline__ float bf2f(unsigned short h){
  union{unsigned u; float f;} v; v.u = ((unsigned)h)<<16; return v.f;
}
__device__ __forceinline__ unsigned short f2bf(float f){
  union{float f; unsigned u;} v; v.f = f;
  unsigned r = v.u + 0x7fffu + ((v.u>>16)&1u);   // RNE
  return (unsigned short)(r>>16);
}
// [*][64]-bf16 tiles, 16B-chunk XOR swizzle on (row&7) to kill ds_read_b128 bank conflicts
__device__ __forceinline__ s8v lds_rd8(const unsigned short* b, int row, int ck){
  return *(const s8v*)&b[(row<<6) + (((ck)^(row&7))<<3)];
}
__device__ __forceinline__ void lds_wr8(unsigned short* b, int row, int ck, s8v v){
  *(s8v*)&b[(row<<6) + (((ck)^(row&7))<<3)] = v;
}

// ---- convert 5 weight matrices fp32 -> bf16 into ws (q,k,v,conv,rs contiguous) ----
__global__ __launch_bounds__(256) void k_wcvt(const float* __restrict__ w0,
    const float* __restrict__ w1, const float* __restrict__ w2,
    const float* __restrict__ w3, const float* __restrict__ w4,
    unsigned short* __restrict__ dst){
  int i = blockIdx.x*256 + threadIdx.x;
  int z = blockIdx.y;
  const float* s = (z==0)?w0:(z==1)?w1:(z==2)?w2:(z==3)?w3:w4;
  dst[z*(E_DIM*C_IN) + i] = f2bf(s[i]);
}

// ---- x (C,S) fp32 -> XaT (S,C) bf16 [relu(bn1)] and XrT (S,C) bf16 [raw] ----
__global__ __launch_bounds__(256) void k_prep(const float* __restrict__ x,
    const float* __restrict__ bw, const float* __restrict__ bb,
    const float* __restrict__ bm, const float* __restrict__ bvar,
    unsigned short* __restrict__ XaT, unsigned short* __restrict__ XrT){
  __shared__ float tile[32][33];
  int tid = threadIdx.x;
  int tx = tid & 31, ty = tid >> 5;
  int s0 = blockIdx.x*32, c0 = blockIdx.y*32;
  #pragma unroll
  for(int p=0;p<4;p++){
    int c = c0 + ty + p*8;
    tile[ty+p*8][tx] = x[c*S_DIM + s0 + tx];
  }
  __syncthreads();
  int cc = c0 + tx;
  float inv  = bw[cc] * rsqrtf(bvar[cc] + EPSV);
  float beta = bb[cc] - bm[cc]*inv;
  #pragma unroll
  for(int p=0;p<4;p++){
    int s = s0 + ty + p*8;
    float v = tile[tx][ty+p*8];
    float a = v*inv + beta; a = a>0.f?a:0.f;
    XaT[s*C_IN + cc] = f2bf(a);
    XrT[s*C_IN + cc] = f2bf(v);
  }
}

// ---- uniform projection GEMM: PT(s,e) = XinT(s,:) . W(e,:) + bias ----
// z=0 Q ->(S,E), z=1 K ->(S,E), z=2 V ->(E,S), z=3 conv(+cbn+relu) ->(S,E)
__global__ __launch_bounds__(256) void k_proj(
    const unsigned short* __restrict__ XaT, const unsigned short* __restrict__ XrT,
    const unsigned short* __restrict__ Wb,
    const float* __restrict__ bq, const float* __restrict__ bk,
    const float* __restrict__ bvb, const float* __restrict__ bc,
    const float* __restrict__ cw, const float* __restrict__ cbb,
    const float* __restrict__ cm, const float* __restrict__ cvv,
    unsigned short* __restrict__ QT, unsigned short* __restrict__ KT,
    unsigned short* __restrict__ Vx, unsigned short* __restrict__ CT){
  int z = blockIdx.z;
  const unsigned short* Xin = (z==3) ? XrT : XaT;
  const unsigned short* W   = Wb + z*(E_DIM*C_IN);
  const float* bias = (z==0)?bq:(z==1)?bk:(z==2)?bvb:bc;

  __shared__ unsigned short Als[128*64];
  __shared__ unsigned short Bls[64*64];
  int tid = threadIdx.x;
  int w = tid>>6, l = tid&63, g = l>>4, c16 = l&15;
  int wr = w>>1, wc = w&1;
  int s0 = blockIdx.x*128, e0 = blockIdx.y*64;

  f4v acc[4][2];
  #pragma unroll
  for(int m=0;m<4;m++)
    #pragma unroll
    for(int n=0;n<2;n++) acc[m][n] = (f4v){0.f,0.f,0.f,0.f};

  for(int kk=0;kk<4;kk++){
    __syncthreads();
    #pragma unroll
    for(int p=0;p<4;p++){
      int ck = p*256 + tid, row = ck>>3, ch = ck&7;
      s8v v = *(const s8v*)&Xin[(s0+row)*C_IN + kk*64 + ch*8];
      lds_wr8(Als, row, ch, v);
    }
    #pragma unroll
    for(int p=0;p<2;p++){
      int ck = p*256 + tid, row = ck>>3, ch = ck&7;
      s8v v = *(const s8v*)&W[(e0+row)*C_IN + kk*64 + ch*8];
      lds_wr8(Bls, row, ch, v);
    }
    __syncthreads();
    #pragma unroll
    for(int kb=0;kb<2;kb++){
      s8v bfr[2];
      #pragma unroll
      for(int n=0;n<2;n++) bfr[n] = lds_rd8(Bls, wc*32 + n*16 + c16, g + kb*4);
      #pragma unroll
      for(int m=0;m<4;m++){
        s8v af = lds_rd8(Als, wr*64 + m*16 + c16, g + kb*4);
        #pragma unroll
        for(int n=0;n<2;n++)
          acc[m][n] = __builtin_amdgcn_mfma_f32_16x16x32_bf16(af, bfr[n], acc[m][n], 0,0,0);
      }
    }
  }
  #pragma unroll
  for(int n=0;n<2;n++){
    int e = e0 + wc*32 + n*16 + c16;
    float bsv = bias[e];
    float cinv = 0.f, cbeta = 0.f;
    if(z==3){ cinv = cw[e]*rsqrtf(cvv[e]+EPSV); cbeta = cbb[e] - cm[e]*cinv; }
    #pragma unroll
    for(int m=0;m<4;m++){
      int sb = s0 + wr*64 + m*16 + g*4;
      if(z==2){
        s4v pk;
        #pragma unroll
        for(int i=0;i<4;i++) pk[i] = (short)f2bf(acc[m][n][i] + bsv);
        *(s4v*)&Vx[e*S_DIM + sb] = pk;
      } else {
        unsigned short* dst = (z==0)?QT:(z==1)?KT:CT;
        #pragma unroll
        for(int i=0;i<4;i++){
          float vv = acc[m][n][i] + bsv;
          if(z==3){ vv = vv*cinv + cbeta; vv = vv>0.f?vv:0.f; }
          dst[(sb+i)*E_DIM + e] = f2bf(vv);
        }
      }
    }
  }
}

// ---- flash attention + fuse(gamma*out + conv_path) -> fusedT (S,E) bf16 ----
// Block: 32 queries, 4 waves. Wave w: qh=w&1 picks 16-query half, kh=w>>1 picks
// key-tile half (tiles kh*32 .. kh*32+31). End: online-softmax merge across kh in LDS.
__global__ __launch_bounds__(256) void k_attn(
    const unsigned short* __restrict__ QT, const unsigned short* __restrict__ KT,
    const unsigned short* __restrict__ Vx, const unsigned short* __restrict__ CT,
    const float* __restrict__ gamma, const float* __restrict__ temp,
    unsigned short* __restrict__ fusedT){
  __shared__ unsigned short Kls[2][64*64];
  __shared__ unsigned short Vls[2][64*64];
  __shared__ unsigned short Pls[4][16*64];
  int tid = threadIdx.x;
  int w = tid>>6, l = tid&63, g = l>>4, c16 = l&15;
  int qh = w&1, kh = w>>1;
  int h = blockIdx.y;
  int q0 = blockIdx.x*32 + qh*16;     // this wave's 16 query rows
  float invT = 1.0f / temp[0];

  // Q fragments (pre-scaled by 1/temperature) live in registers all kernel
  s8v qf0, qf1;
  {
    s8v r0 = *(const s8v*)&QT[(q0+c16)*E_DIM + h*HD + g*8];
    s8v r1 = *(const s8v*)&QT[(q0+c16)*E_DIM + h*HD + g*8 + 32];
    #pragma unroll
    for(int j=0;j<8;j++){
      qf0[j] = (short)f2bf(bf2f((unsigned short)r0[j])*invT);
      qf1[j] = (short)f2bf(bf2f((unsigned short)r1[j])*invT);
    }
  }

  f4v oacc[4];
  #pragma unroll
  for(int dt=0;dt<4;dt++) oacc[dt] = (f4v){0.f,0.f,0.f,0.f};
  float mrun[4] = {-1e30f,-1e30f,-1e30f,-1e30f};
  float lrun[4] = {0.f,0.f,0.f,0.f};
  unsigned short* Pw = Pls[w];

  for(int t=0;t<32;t++){
    __syncthreads();
    #pragma unroll
    for(int b=0;b<2;b++){
      int sK = (b*32 + t)*64;
      #pragma unroll
      for(int p=0;p<2;p++){               // K tile: 64 keys x 64 d
        int ck = p*256 + tid, row = ck>>3, ch = ck&7;
        s8v v = *(const s8v*)&KT[(sK+row)*E_DIM + h*HD + ch*8];
        lds_wr8(Kls[b], row, ch, v);
      }
      #pragma unroll
      for(int p=0;p<2;p++){               // V tile: Vt[d][key]
        int ck = p*256 + tid, row = ck>>3, ch = ck&7;
        s8v v = *(const s8v*)&Vx[(h*HD+row)*S_DIM + sK + ch*8];
        lds_wr8(Vls[b], row, ch, v);
      }
    }
    __syncthreads();

    const unsigned short* Kw = Kls[kh];
    const unsigned short* Vw = Vls[kh];

    // S = Q K^T : sacc[kt] rows=q (g*4+i), cols=key (c16 + 16*kt)
    f4v sacc[4];
    #pragma unroll
    for(int kt=0;kt<4;kt++) sacc[kt] = (f4v){0.f,0.f,0.f,0.f};
    #pragma unroll
    for(int kt=0;kt<4;kt++){
      int r = kt*16 + c16;
      s8v kf0 = lds_rd8(Kw, r, g);
      s8v kf1 = lds_rd8(Kw, r, g+4);
      sacc[kt] = __builtin_amdgcn_mfma_f32_16x16x32_bf16(qf0, kf0, sacc[kt],0,0,0);
      sacc[kt] = __builtin_amdgcn_mfma_f32_16x16x32_bf16(qf1, kf1, sacc[kt],0,0,0);
    }
    // online softmax: row lives across the 16 lanes of a g-group
    float tm[4] = {-1e30f,-1e30f,-1e30f,-1e30f};
    #pragma unroll
    for(int kt=0;kt<4;kt++)
      #pragma unroll
      for(int i=0;i<4;i++)
        tm[i] = fmaxf(tm[i], sacc[kt][i]);
    #pragma unroll
    for(int off=8; off>=1; off>>=1)
      #pragma unroll
      for(int i=0;i<4;i++)
        tm[i] = fmaxf(tm[i], __shfl_xor(tm[i], off));
    float scl[4], ts[4];
    #pragma unroll
    for(int i=0;i<4;i++){
      float mn = fmaxf(mrun[i], tm[i]);
      scl[i] = __expf(mrun[i]-mn);
      mrun[i] = mn;
      ts[i] = 0.f;
    }
    #pragma unroll
    for(int kt=0;kt<4;kt++){
      int colb = c16 + kt*16;
      int ckk = colb>>3, cre = colb&7;
      #pragma unroll
      for(int i=0;i<4;i++){
        float pv = __expf(sacc[kt][i] - mrun[i]);
        ts[i] += pv;
        int row = g*4+i;
        Pw[(row<<6) + ((ckk^(row&7))<<3) + cre] = f2bf(pv);
      }
    }
    #pragma unroll
    for(int off=8; off>=1; off>>=1)
      #pragma unroll
      for(int i=0;i<4;i++)
        ts[i] += __shfl_xor(ts[i], off);
    #pragma unroll
    for(int i=0;i<4;i++) lrun[i] = lrun[i]*scl[i] + ts[i];
    #pragma unroll
    for(int dt=0;dt<4;dt++)
      #pragma unroll
      for(int i=0;i<4;i++) oacc[dt][i] *= scl[i];
    // O += P V  (P re-read from per-wave LDS in A-fragment layout)
    #pragma unroll
    for(int kb=0;kb<2;kb++){
      s8v pf = lds_rd8(Pw, c16, g + kb*4);
      #pragma unroll
      for(int dt=0;dt<4;dt++){
        s8v vf = lds_rd8(Vw, dt*16 + c16, g + kb*4);
        oacc[dt] = __builtin_amdgcn_mfma_f32_16x16x32_bf16(pf, vf, oacc[dt],0,0,0);
      }
    }
  }

  // ---- merge the two KV-halves (kh=1 -> LDS -> kh=0 combines) ----
  __syncthreads();
  float* mb = (float*)Kls;                 // reuse: 2 * 64 * 25 floats = 12.5KB <= 16KB
  if(kh==1){
    float* dst = mb + (qh*64 + l)*25;
    #pragma unroll
    for(int dt=0;dt<4;dt++)
      #pragma unroll
      for(int i=0;i<4;i++) dst[dt*4+i] = oacc[dt][i];
    #pragma unroll
    for(int i=0;i<4;i++){ dst[16+i] = mrun[i]; dst[20+i] = lrun[i]; }
  }
  __syncthreads();
  if(kh==0){
    const float* src = mb + (qh*64 + l)*25;
    #pragma unroll
    for(int i=0;i<4;i++){
      float m1 = src[16+i], l1 = src[20+i];
      float mn = fmaxf(mrun[i], m1);
      float a0 = __expf(mrun[i]-mn), a1 = __expf(m1-mn);
      lrun[i] = lrun[i]*a0 + l1*a1;
      #pragma unroll
      for(int dt=0;dt<4;dt++)
        oacc[dt][i] = oacc[dt][i]*a0 + src[dt*4+i]*a1;
    }
    // epilogue: fusedT[s][e] = gamma*O/l + conv_path
    float ga = gamma[0];
    float rl[4];
    #pragma unroll
    for(int i=0;i<4;i++) rl[i] = 1.0f/lrun[i];
    #pragma unroll
    for(int dt=0;dt<4;dt++){
      int e = h*HD + dt*16 + c16;
      #pragma unroll
      for(int i=0;i<4;i++){
        int s = q0 + g*4 + i;
        float o = oacc[dt][i]*rl[i]*ga + bf2f(CT[s*E_DIM + e]);
        fusedT[s*E_DIM + e] = f2bf(o);
      }
    }
  }
}

// ---- final: out(c,s) = gelu(rbn(rs_w . fused + rs_b)) fp32 ----
__global__ __launch_bounds__(256) void k_final(
    const unsigned short* __restrict__ Wrs,
    const unsigned short* __restrict__ fusedT,
    const float* __restrict__ rsb,
    const float* __restrict__ rw, const float* __restrict__ rbb,
    const float* __restrict__ rm, const float* __restrict__ rv,
    float* __restrict__ out){
  __shared__ unsigned short Als[64*64];
  __shared__ unsigned short Bls[128*64];
  int tid = threadIdx.x;
  int w = tid>>6, l = tid&63, g = l>>4, c16 = l&15;
  int wr = w>>1, wc = w&1;
  int sB0 = blockIdx.x*128, c0 = blockIdx.y*64;
  f4v acc[2][4];
  #pragma unroll
  for(int m=0;m<2;m++)
    #pragma unroll
    for(int n=0;n<4;n++) acc[m][n]=(f4v){0.f,0.f,0.f,0.f};
  for(int kk=0;kk<8;kk++){
    __syncthreads();
    #pragma unroll
    for(int p=0;p<2;p++){
      int ck = p*256+tid, row=ck>>3, ch=ck&7;
      s8v v = *(const s8v*)&Wrs[(c0+row)*E_DIM + kk*64 + ch*8];
      lds_wr8(Als, row, ch, v);
    }
    #pragma unroll
    for(int p=0;p<4;p++){
      int ck = p*256+tid, row=ck>>3, ch=ck&7;
      s8v v = *(const s8v*)&fusedT[(sB0+row)*E_DIM + kk*64 + ch*8];
      lds_wr8(Bls, row, ch, v);
    }
    __syncthreads();
    #pragma unroll
    for(int kb=0;kb<2;kb++){
      s8v af[2]; s8v bfr[4];
      #pragma unroll
      for(int m=0;m<2;m++) af[m] = lds_rd8(Als, wr*32 + m*16 + c16, g + kb*4);
      #pragma unroll
      for(int n=0;n<4;n++) bfr[n] = lds_rd8(Bls, wc*64 + n*16 + c16, g + kb*4);
      #pragma unroll
      for(int m=0;m<2;m++)
        #pragma unroll
        for(int n=0;n<4;n++)
          acc[m][n] = __builtin_amdgcn_mfma_f32_16x16x32_bf16(af[m], bfr[n], acc[m][n],0,0,0);
    }
  }
  #pragma unroll
  for(int m=0;m<2;m++){
    #pragma unroll
    for(int i=0;i<4;i++){
      int c = c0 + wr*32 + m*16 + g*4 + i;
      float bias = rsb[c];
      float rinv = rw[c]*rsqrtf(rv[c]+EPSV);
      float rbeta = rbb[c] - rm[c]*rinv;
      #pragma unroll
      for(int n=0;n<4;n++){
        int s = sB0 + wc*64 + n*16 + c16;
        float vv = acc[m][n][i] + bias;
        vv = vv*rinv + rbeta;
        out[c*S_DIM + s] = 0.5f*vv*(1.0f + erff(vv*0.70710678118f));
      }
    }
  }
}

extern "C" void kernel_launch(void* const* d_in, const int* in_sizes, int n_in,
                              void* d_out, int out_size, void* d_ws, size_t ws_size,
                              hipStream_t stream){
  const float* x     = (const float*)d_in[0];
  const float* bn1w  = (const float*)d_in[1];
  const float* bn1b  = (const float*)d_in[2];
  const float* bn1m  = (const float*)d_in[3];
  const float* bn1v  = (const float*)d_in[4];
  const float* Wq    = (const float*)d_in[5];
  const float* bq    = (const float*)d_in[6];
  const float* Wk    = (const float*)d_in[7];
  const float* bk    = (const float*)d_in[8];
  const float* Wv    = (const float*)d_in[9];
  const float* bv    = (const float*)d_in[10];
  const float* gamma = (const float*)d_in[11];
  const float* temp  = (const float*)d_in[12];
  const float* convw = (const float*)d_in[13];
  const float* convb = (const float*)d_in[14];
  const float* cbnw  = (const float*)d_in[15];
  const float* cbnb  = (const float*)d_in[16];
  const float* cbnm  = (const float*)d_in[17];
  const float* cbnv  = (const float*)d_in[18];
  const float* rsw   = (const float*)d_in[19];
  const float* rsbp  = (const float*)d_in[20];
  const float* rbnw  = (const float*)d_in[21];
  const float* rbnb  = (const float*)d_in[22];
  const float* rbnm  = (const float*)d_in[23];
  const float* rbnv  = (const float*)d_in[24];
  float* out = (float*)d_out;

  unsigned short* ws  = (unsigned short*)d_ws;
  unsigned short* XaT = ws;                          // (S,C) bf16
  unsigned short* XrT = XaT + S_DIM*C_IN;            // (S,C) bf16
  unsigned short* Wb  = XrT + S_DIM*C_IN;            // q,k,v,conv weights bf16
  unsigned short* Wrs = Wb + 4*E_DIM*C_IN;           // rs weight bf16 (256x512)
  unsigned short* QT  = Wrs + C_IN*E_DIM;            // (S,E)
  unsigned short* KT  = QT + S_DIM*E_DIM;            // (S,E)
  unsigned short* Vx  = KT + S_DIM*E_DIM;            // (E,S)
  unsigned short* CT  = Vx + S_DIM*E_DIM;            // (S,E) conv path
  unsigned short* fusedT = CT + S_DIM*E_DIM;         // (S,E)

  k_wcvt<<<dim3(512,5),256,0,stream>>>(Wq, Wk, Wv, convw, rsw, Wb);
  k_prep<<<dim3(128,8),256,0,stream>>>(x, bn1w, bn1b, bn1m, bn1v, XaT, XrT);
  k_proj<<<dim3(32,8,4),256,0,stream>>>(XaT, XrT, Wb, bq, bk, bv, convb,
                                        cbnw, cbnb, cbnm, cbnv, QT, KT, Vx, CT);
  k_attn<<<dim3(128,8),256,0,stream>>>(QT, KT, Vx, CT, gamma, temp, fusedT);
  k_final<<<dim3(32,4),256,0,stream>>>(Wrs, fusedT, rsbp, rbnw, rbnb, rbnm, rbnv, out);
}

// Round 3
// 94.641 us; speedup vs baseline: 1.8690x; 1.8690x over previous
//
#include <hip/hip_runtime.h>

#define S_DIM 4096
#define C_IN  256
#define E_DIM 512
#define HD    64
#define EPSV  1e-5f

typedef __attribute__((ext_vector_type(8))) short s8v;
typedef __attribute__((ext_vector_type(4))) short s4v;
typedef __attribute__((ext_vector_type(4))) float f4v;
typedef __attribute__((ext_vector_type(16))) float f16v;

__device__ __forceinline__ float bf2f(unsigned short h){
  union{unsigned u; float f;} v; v.u = ((unsigned)h)<<16; return v.f;
}
__device__ __forceinline__ unsigned short f2bf(float f){
  union{float f; unsigned u;} v; v.f = f;
  unsigned r = v.u + 0x7fffu + ((v.u>>16)&1u);   // RNE
  return (unsigned short)(r>>16);
}
__device__ __forceinline__ unsigned cvtpk_bf16(float lo, float hi_){
  unsigned r;
  asm("v_cvt_pk_bf16_f32 %0, %1, %2" : "=v"(r) : "v"(lo), "v"(hi_));
  return r;
}
// [*][64]-bf16 tiles, 16B-chunk XOR swizzle on (row&7) to kill bank conflicts
__device__ __forceinline__ s8v lds_rd8(const unsigned short* b, int row, int ck){
  return *(const s8v*)&b[(row<<6) + (((ck)^(row&7))<<3)];
}
__device__ __forceinline__ s4v lds_rd4(const unsigned short* b, int row, int eoff){
  int ck = eoff>>3, sub = eoff&7;
  return *(const s4v*)&b[(row<<6) + ((ck^(row&7))<<3) + sub];
}
__device__ __forceinline__ void lds_wr8(unsigned short* b, int row, int ck, s8v v){
  *(s8v*)&b[(row<<6) + (((ck)^(row&7))<<3)] = v;
}

// ---- convert 5 weight matrices fp32 -> bf16 into ws (q,k,v,conv,rs contiguous) ----
__global__ __launch_bounds__(256) void k_wcvt(const float* __restrict__ w0,
    const float* __restrict__ w1, const float* __restrict__ w2,
    const float* __restrict__ w3, const float* __restrict__ w4,
    unsigned short* __restrict__ dst){
  int i = blockIdx.x*256 + threadIdx.x;
  int z = blockIdx.y;
  const float* s = (z==0)?w0:(z==1)?w1:(z==2)?w2:(z==3)?w3:w4;
  dst[z*(E_DIM*C_IN) + i] = f2bf(s[i]);
}

// ---- x (C,S) fp32 -> XaT (S,C) bf16 [relu(bn1)] and XrT (S,C) bf16 [raw] ----
__global__ __launch_bounds__(256) void k_prep(const float* __restrict__ x,
    const float* __restrict__ bw, const float* __restrict__ bb,
    const float* __restrict__ bm, const float* __restrict__ bvar,
    unsigned short* __restrict__ XaT, unsigned short* __restrict__ XrT){
  __shared__ float tile[32][33];
  int tid = threadIdx.x;
  int tx = tid & 31, ty = tid >> 5;
  int s0 = blockIdx.x*32, c0 = blockIdx.y*32;
  #pragma unroll
  for(int p=0;p<4;p++){
    int c = c0 + ty + p*8;
    tile[ty+p*8][tx] = x[c*S_DIM + s0 + tx];
  }
  __syncthreads();
  int cc = c0 + tx;
  float inv  = bw[cc] * rsqrtf(bvar[cc] + EPSV);
  float beta = bb[cc] - bm[cc]*inv;
  #pragma unroll
  for(int p=0;p<4;p++){
    int s = s0 + ty + p*8;
    float v = tile[tx][ty+p*8];
    float a = v*inv + beta; a = a>0.f?a:0.f;
    XaT[s*C_IN + cc] = f2bf(a);
    XrT[s*C_IN + cc] = f2bf(v);
  }
}

// ---- uniform projection GEMM: PT(s,e) = XinT(s,:) . W(e,:) + bias ----
// z=0 Q ->(S,E), z=1 K ->(S,E), z=2 V ->(E,S), z=3 conv(+cbn+relu) ->(S,E)
__global__ __launch_bounds__(256) void k_proj(
    const unsigned short* __restrict__ XaT, const unsigned short* __restrict__ XrT,
    const unsigned short* __restrict__ Wb,
    const float* __restrict__ bq, const float* __restrict__ bk,
    const float* __restrict__ bvb, const float* __restrict__ bc,
    const float* __restrict__ cw, const float* __restrict__ cbb,
    const float* __restrict__ cm, const float* __restrict__ cvv,
    unsigned short* __restrict__ QT, unsigned short* __restrict__ KT,
    unsigned short* __restrict__ Vx, unsigned short* __restrict__ CT){
  int z = blockIdx.z;
  const unsigned short* Xin = (z==3) ? XrT : XaT;
  const unsigned short* W   = Wb + z*(E_DIM*C_IN);
  const float* bias = (z==0)?bq:(z==1)?bk:(z==2)?bvb:bc;

  __shared__ unsigned short Als[128*64];
  __shared__ unsigned short Bls[64*64];
  int tid = threadIdx.x;
  int w = tid>>6, l = tid&63, g = l>>4, c16 = l&15;
  int wr = w>>1, wc = w&1;
  int s0 = blockIdx.x*128, e0 = blockIdx.y*64;

  f4v acc[4][2];
  #pragma unroll
  for(int m=0;m<4;m++)
    #pragma unroll
    for(int n=0;n<2;n++) acc[m][n] = (f4v){0.f,0.f,0.f,0.f};

  for(int kk=0;kk<4;kk++){
    __syncthreads();
    #pragma unroll
    for(int p=0;p<4;p++){
      int ck = p*256 + tid, row = ck>>3, ch = ck&7;
      s8v v = *(const s8v*)&Xin[(s0+row)*C_IN + kk*64 + ch*8];
      lds_wr8(Als, row, ch, v);
    }
    #pragma unroll
    for(int p=0;p<2;p++){
      int ck = p*256 + tid, row = ck>>3, ch = ck&7;
      s8v v = *(const s8v*)&W[(e0+row)*C_IN + kk*64 + ch*8];
      lds_wr8(Bls, row, ch, v);
    }
    __syncthreads();
    #pragma unroll
    for(int kb=0;kb<2;kb++){
      s8v bfr[2];
      #pragma unroll
      for(int n=0;n<2;n++) bfr[n] = lds_rd8(Bls, wc*32 + n*16 + c16, g + kb*4);
      #pragma unroll
      for(int m=0;m<4;m++){
        s8v af = lds_rd8(Als, wr*64 + m*16 + c16, g + kb*4);
        #pragma unroll
        for(int n=0;n<2;n++)
          acc[m][n] = __builtin_amdgcn_mfma_f32_16x16x32_bf16(af, bfr[n], acc[m][n], 0,0,0);
      }
    }
  }
  #pragma unroll
  for(int n=0;n<2;n++){
    int e = e0 + wc*32 + n*16 + c16;
    float bsv = bias[e];
    float cinv = 0.f, cbeta = 0.f;
    if(z==3){ cinv = cw[e]*rsqrtf(cvv[e]+EPSV); cbeta = cbb[e] - cm[e]*cinv; }
    #pragma unroll
    for(int m=0;m<4;m++){
      int sb = s0 + wr*64 + m*16 + g*4;
      if(z==2){
        s4v pk;
        #pragma unroll
        for(int i=0;i<4;i++) pk[i] = (short)f2bf(acc[m][n][i] + bsv);
        *(s4v*)&Vx[e*S_DIM + sb] = pk;
      } else {
        unsigned short* dst = (z==0)?QT:(z==1)?KT:CT;
        #pragma unroll
        for(int i=0;i<4;i++){
          float vv = acc[m][n][i] + bsv;
          if(z==3){ vv = vv*cinv + cbeta; vv = vv>0.f?vv:0.f; }
          dst[(sb+i)*E_DIM + e] = f2bf(vv);
        }
      }
    }
  }
}

// ---- flash attention (fixed-max softmax) + fuse -> fusedT (S,E) bf16 ----
// Block: 64 queries, 4 waves = (qh: 32-q half, kh: KV half). 32x32x16 MFMA.
// Swapped QK^T (A=K, B=Q in regs) => P lives in regs with lane index = q;
// PV A-frags built in-register via v_cvt_pk_bf16_f32 with permuted k-slots.
__global__ __launch_bounds__(256) void k_attn(
    const unsigned short* __restrict__ QT, const unsigned short* __restrict__ KT,
    const unsigned short* __restrict__ Vx, const unsigned short* __restrict__ CT,
    const float* __restrict__ gamma, const float* __restrict__ temp,
    unsigned short* __restrict__ fusedT){
  __shared__ unsigned short SM[4*4096];  // K[kh0],K[kh1],V[kh0],V[kh1] 8KB tiles
  int tid = threadIdx.x;
  int w = tid>>6, l = tid&63, l31 = l&31, hi = l>>5;
  int qh = w&1, kh = w>>1;
  int h = blockIdx.y;
  int qb = blockIdx.x*64;
  int q = qb + qh*32 + l31;
  float scl = 1.0f / temp[0];

  const unsigned short* Kb = SM + kh*4096;
  const unsigned short* Vb = SM + 8192 + kh*4096;

  // Q B-fragments (pre-scaled by 1/T), one per 16-wide k-slice of d
  s8v qf[4];
  #pragma unroll
  for(int ks=0;ks<4;ks++){
    s8v r = *(const s8v*)&QT[q*E_DIM + h*HD + ks*16 + hi*8];
    #pragma unroll
    for(int j=0;j<8;j++) qf[ks][j] = (short)f2bf(bf2f((unsigned short)r[j])*scl);
  }

  f16v oacc0, oacc1;
  #pragma unroll
  for(int r=0;r<16;r++){ oacc0[r]=0.f; oacc1[r]=0.f; }
  float lrun = 0.f;

  for(int t=0;t<32;t++){
    __syncthreads();
    #pragma unroll
    for(int p=0;p<8;p++){                       // stage K,V tiles for both kh
      int flat = p*256 + tid;
      int tile = flat>>9, cid = flat&511, row = cid>>3, ch = cid&7;
      int khp = tile&1, isV = tile>>1;
      int sK = ((khp<<5) + t)<<6;
      s8v v;
      if(!isV) v = *(const s8v*)&KT[(sK+row)*E_DIM + h*HD + ch*8];
      else     v = *(const s8v*)&Vx[(h*HD+row)*S_DIM + sK + ch*8];
      lds_wr8(SM + tile*4096, row, ch, v);
    }
    __syncthreads();

    #pragma unroll
    for(int sub=0;sub<2;sub++){                 // two 32-key sub-tiles
      int krow = sub*32 + l31;
      f16v d;
      #pragma unroll
      for(int r=0;r<16;r++) d[r]=0.f;
      #pragma unroll
      for(int ks=0;ks<4;ks++){
        s8v kf = lds_rd8(Kb, krow, ks*2 + hi);
        d = __builtin_amdgcn_mfma_f32_32x32x16_bf16(kf, qf[ks], d, 0,0,0);
      }
      // D[key-reg][q=l31]; fixed-max softmax: P = exp(s)
      float e[16];
      float ls = 0.f;
      #pragma unroll
      for(int r=0;r<16;r++){ e[r] = __expf(d[r]); ls += e[r]; }
      lrun += ls;
      // PV A-frags in-register (permuted k-slots match D-reg key order)
      union{ s8v v; unsigned u[4]; } pa0, pa1;
      #pragma unroll
      for(int j=0;j<4;j++){
        pa0.u[j] = cvtpk_bf16(e[2*j],   e[2*j+1]);
        pa1.u[j] = cvtpk_bf16(e[8+2*j], e[8+2*j+1]);
      }
      #pragma unroll
      for(int dt=0;dt<2;dt++){
        int vrow = dt*32 + l31;
        union{ s8v v; s4v h2[2]; } vf;
        f16v& oa = dt ? oacc1 : oacc0;
        vf.h2[0] = lds_rd4(Vb, vrow, sub*32 + hi*4);
        vf.h2[1] = lds_rd4(Vb, vrow, sub*32 + hi*4 + 8);
        oa = __builtin_amdgcn_mfma_f32_32x32x16_bf16(pa0.v, vf.v, oa, 0,0,0);
        vf.h2[0] = lds_rd4(Vb, vrow, sub*32 + 16 + hi*4);
        vf.h2[1] = lds_rd4(Vb, vrow, sub*32 + 16 + hi*4 + 8);
        oa = __builtin_amdgcn_mfma_f32_32x32x16_bf16(pa1.v, vf.v, oa, 0,0,0);
      }
    }
  }

  // total l per q over this wave's keys (lanes l and l^32 hold complements)
  lrun += __shfl_xor(lrun, 32);

  // additive merge across kh (shared fixed max => plain sums)
  __syncthreads();
  float* mb = (float*)SM;              // 128 lanes x 33 floats = 16.9KB
  float* l_lds = mb + 128*33;          // 64 floats
  if(kh==1){
    float* dst = mb + (qh*64 + l)*33;
    #pragma unroll
    for(int r=0;r<16;r++){ dst[r] = oacc0[r]; dst[16+r] = oacc1[r]; }
    dst[32] = lrun;
  }
  __syncthreads();
  float ltot = 0.f;
  if(kh==0){
    const float* src = mb + (qh*64 + l)*33;
    #pragma unroll
    for(int r=0;r<16;r++){ oacc0[r] += src[r]; oacc1[r] += src[16+r]; }
    ltot = lrun + src[32];
  }
  if(kh==0 && hi==0) l_lds[qh*32 + l31] = ltot;
  __syncthreads();
  if(kh==0){
    float ga = gamma[0];
    #pragma unroll
    for(int dt=0;dt<2;dt++){
      const f16v& oa = dt ? oacc1 : oacc0;
      int e = h*HD + dt*32 + l31;
      #pragma unroll
      for(int g4=0;g4<4;g4++){
        float4 lv = *(float4*)&l_lds[qh*32 + g4*8 + hi*4];
        float la[4] = {lv.x, lv.y, lv.z, lv.w};
        #pragma unroll
        for(int j=0;j<4;j++){
          int r = g4*4 + j;
          int qrow = qb + qh*32 + j + g4*8 + hi*4;
          float o = oa[r]/la[j]*ga + bf2f(CT[qrow*E_DIM + e]);
          fusedT[qrow*E_DIM + e] = f2bf(o);
        }
      }
    }
  }
}

// ---- final: out(c,s) = gelu(rbn(rs_w . fused + rs_b)) fp32 ----
__global__ __launch_bounds__(256) void k_final(
    const unsigned short* __restrict__ Wrs,
    const unsigned short* __restrict__ fusedT,
    const float* __restrict__ rsb,
    const float* __restrict__ rw, const float* __restrict__ rbb,
    const float* __restrict__ rm, const float* __restrict__ rv,
    float* __restrict__ out){
  __shared__ unsigned short Als[64*64];
  __shared__ unsigned short Bls[128*64];
  int tid = threadIdx.x;
  int w = tid>>6, l = tid&63, g = l>>4, c16 = l&15;
  int wr = w>>1, wc = w&1;
  int sB0 = blockIdx.x*128, c0 = blockIdx.y*64;
  f4v acc[2][4];
  #pragma unroll
  for(int m=0;m<2;m++)
    #pragma unroll
    for(int n=0;n<4;n++) acc[m][n]=(f4v){0.f,0.f,0.f,0.f};
  for(int kk=0;kk<8;kk++){
    __syncthreads();
    #pragma unroll
    for(int p=0;p<2;p++){
      int ck = p*256+tid, row=ck>>3, ch=ck&7;
      s8v v = *(const s8v*)&Wrs[(c0+row)*E_DIM + kk*64 + ch*8];
      lds_wr8(Als, row, ch, v);
    }
    #pragma unroll
    for(int p=0;p<4;p++){
      int ck = p*256+tid, row=ck>>3, ch=ck&7;
      s8v v = *(const s8v*)&fusedT[(sB0+row)*E_DIM + kk*64 + ch*8];
      lds_wr8(Bls, row, ch, v);
    }
    __syncthreads();
    #pragma unroll
    for(int kb=0;kb<2;kb++){
      s8v af[2]; s8v bfr[4];
      #pragma unroll
      for(int m=0;m<2;m++) af[m] = lds_rd8(Als, wr*32 + m*16 + c16, g + kb*4);
      #pragma unroll
      for(int n=0;n<4;n++) bfr[n] = lds_rd8(Bls, wc*64 + n*16 + c16, g + kb*4);
      #pragma unroll
      for(int m=0;m<2;m++)
        #pragma unroll
        for(int n=0;n<4;n++)
          acc[m][n] = __builtin_amdgcn_mfma_f32_16x16x32_bf16(af[m], bfr[n], acc[m][n],0,0,0);
    }
  }
  #pragma unroll
  for(int m=0;m<2;m++){
    #pragma unroll
    for(int i=0;i<4;i++){
      int c = c0 + wr*32 + m*16 + g*4 + i;
      float bias = rsb[c];
      float rinv = rw[c]*rsqrtf(rv[c]+EPSV);
      float rbeta = rbb[c] - rm[c]*rinv;
      #pragma unroll
      for(int n=0;n<4;n++){
        int s = sB0 + wc*64 + n*16 + c16;
        float vv = acc[m][n][i] + bias;
        vv = vv*rinv + rbeta;
        out[c*S_DIM + s] = 0.5f*vv*(1.0f + erff(vv*0.70710678118f));
      }
    }
  }
}

extern "C" void kernel_launch(void* const* d_in, const int* in_sizes, int n_in,
                              void* d_out, int out_size, void* d_ws, size_t ws_size,
                              hipStream_t stream){
  const float* x     = (const float*)d_in[0];
  const float* bn1w  = (const float*)d_in[1];
  const float* bn1b  = (const float*)d_in[2];
  const float* bn1m  = (const float*)d_in[3];
  const float* bn1v  = (const float*)d_in[4];
  const float* Wq    = (const float*)d_in[5];
  const float* bq    = (const float*)d_in[6];
  const float* Wk    = (const float*)d_in[7];
  const float* bk    = (const float*)d_in[8];
  const float* Wv    = (const float*)d_in[9];
  const float* bv    = (const float*)d_in[10];
  const float* gamma = (const float*)d_in[11];
  const float* temp  = (const float*)d_in[12];
  const float* convw = (const float*)d_in[13];
  const float* convb = (const float*)d_in[14];
  const float* cbnw  = (const float*)d_in[15];
  const float* cbnb  = (const float*)d_in[16];
  const float* cbnm  = (const float*)d_in[17];
  const float* cbnv  = (const float*)d_in[18];
  const float* rsw   = (const float*)d_in[19];
  const float* rsbp  = (const float*)d_in[20];
  const float* rbnw  = (const float*)d_in[21];
  const float* rbnb  = (const float*)d_in[22];
  const float* rbnm  = (const float*)d_in[23];
  const float* rbnv  = (const float*)d_in[24];
  float* out = (float*)d_out;

  unsigned short* ws  = (unsigned short*)d_ws;
  unsigned short* XaT = ws;                          // (S,C) bf16
  unsigned short* XrT = XaT + S_DIM*C_IN;            // (S,C) bf16
  unsigned short* Wb  = XrT + S_DIM*C_IN;            // q,k,v,conv weights bf16
  unsigned short* Wrs = Wb + 4*E_DIM*C_IN;           // rs weight bf16 (256x512)
  unsigned short* QT  = Wrs + C_IN*E_DIM;            // (S,E)
  unsigned short* KT  = QT + S_DIM*E_DIM;            // (S,E)
  unsigned short* Vx  = KT + S_DIM*E_DIM;            // (E,S)
  unsigned short* CT  = Vx + S_DIM*E_DIM;            // (S,E) conv path
  unsigned short* fusedT = CT + S_DIM*E_DIM;         // (S,E)

  k_wcvt<<<dim3(512,5),256,0,stream>>>(Wq, Wk, Wv, convw, rsw, Wb);
  k_prep<<<dim3(128,8),256,0,stream>>>(x, bn1w, bn1b, bn1m, bn1v, XaT, XrT);
  k_proj<<<dim3(32,8,4),256,0,stream>>>(XaT, XrT, Wb, bq, bk, bv, convb,
                                        cbnw, cbnb, cbnm, cbnv, QT, KT, Vx, CT);
  k_attn<<<dim3(64,8),256,0,stream>>>(QT, KT, Vx, CT, gamma, temp, fusedT);
  k_final<<<dim3(32,4),256,0,stream>>>(Wrs, fusedT, rsbp, rbnw, rbnb, rbnm, rbnv, out);
}

// Round 4
// 94.257 us; speedup vs baseline: 1.8766x; 1.0041x over previous
//
#include <hip/hip_runtime.h>

#define S_DIM 4096
#define C_IN  256
#define E_DIM 512
#define HD    64
#define EPSV  1e-5f

typedef __attribute__((ext_vector_type(8))) short s8v;
typedef __attribute__((ext_vector_type(4))) short s4v;
typedef __attribute__((ext_vector_type(4))) float f4v;
typedef __attribute__((ext_vector_type(16))) float f16v;

__device__ __forceinline__ float bf2f(unsigned short h){
  union{unsigned u; float f;} v; v.u = ((unsigned)h)<<16; return v.f;
}
__device__ __forceinline__ unsigned short f2bf(float f){
  union{float f; unsigned u;} v; v.f = f;
  unsigned r = v.u + 0x7fffu + ((v.u>>16)&1u);   // RNE
  return (unsigned short)(r>>16);
}
__device__ __forceinline__ unsigned cvtpk_bf16(float lo, float hi_){
  unsigned r;
  asm("v_cvt_pk_bf16_f32 %0, %1, %2" : "=v"(r) : "v"(lo), "v"(hi_));
  return r;
}
// 16B-chunk XOR swizzle (rows of 64 bf16)
__device__ __forceinline__ s8v lds_rd8(const unsigned short* b, int row, int ck){
  return *(const s8v*)&b[(row<<6) + (((ck)^(row&7))<<3)];
}
__device__ __forceinline__ void lds_wr8(unsigned short* b, int row, int ck, s8v v){
  *(s8v*)&b[(row<<6) + (((ck)^(row&7))<<3)] = v;
}
// 8B-granular XOR swizzle for V tile: slot8 = q4 ^ (row&15)
__device__ __forceinline__ s4v lds_rd4q(const unsigned short* b, int row, int q4){
  return *(const s4v*)&b[(row<<6) + (((q4)^(row&15))<<2)];
}
__device__ __forceinline__ void lds_wr4q(unsigned short* b, int row, int q4, s4v v){
  *(s4v*)&b[(row<<6) + (((q4)^(row&15))<<2)] = v;
}

// ---- convert 5 weight matrices fp32 -> bf16 into ws ----
__global__ __launch_bounds__(256) void k_wcvt(const float* __restrict__ w0,
    const float* __restrict__ w1, const float* __restrict__ w2,
    const float* __restrict__ w3, const float* __restrict__ w4,
    unsigned short* __restrict__ dst){
  int i = blockIdx.x*256 + threadIdx.x;
  int z = blockIdx.y;
  const float* s = (z==0)?w0:(z==1)?w1:(z==2)?w2:(z==3)?w3:w4;
  dst[z*(E_DIM*C_IN) + i] = f2bf(s[i]);
}

// ---- x (C,S) fp32 -> XaT (S,C) bf16 [relu(bn1)] and XrT (S,C) bf16 [raw] ----
__global__ __launch_bounds__(256) void k_prep(const float* __restrict__ x,
    const float* __restrict__ bw, const float* __restrict__ bb,
    const float* __restrict__ bm, const float* __restrict__ bvar,
    unsigned short* __restrict__ XaT, unsigned short* __restrict__ XrT){
  __shared__ float tile[32][33];
  int tid = threadIdx.x;
  int tx = tid & 31, ty = tid >> 5;
  int s0 = blockIdx.x*32, c0 = blockIdx.y*32;
  #pragma unroll
  for(int p=0;p<4;p++){
    int c = c0 + ty + p*8;
    tile[ty+p*8][tx] = x[c*S_DIM + s0 + tx];
  }
  __syncthreads();
  int cc = c0 + tx;
  float inv  = bw[cc] * rsqrtf(bvar[cc] + EPSV);
  float beta = bb[cc] - bm[cc]*inv;
  #pragma unroll
  for(int p=0;p<4;p++){
    int s = s0 + ty + p*8;
    float v = tile[tx][ty+p*8];
    float a = v*inv + beta; a = a>0.f?a:0.f;
    XaT[s*C_IN + cc] = f2bf(a);
    XrT[s*C_IN + cc] = f2bf(v);
  }
}

// ---- uniform projection GEMM ----
// z=0 Q ->(S,E), z=1 K ->(S,E), z=2 V ->(E,S), z=3 conv(+cbn+relu) ->(S,E)
__global__ __launch_bounds__(256) void k_proj(
    const unsigned short* __restrict__ XaT, const unsigned short* __restrict__ XrT,
    const unsigned short* __restrict__ Wb,
    const float* __restrict__ bq, const float* __restrict__ bk,
    const float* __restrict__ bvb, const float* __restrict__ bc,
    const float* __restrict__ cw, const float* __restrict__ cbb,
    const float* __restrict__ cm, const float* __restrict__ cvv,
    unsigned short* __restrict__ QT, unsigned short* __restrict__ KT,
    unsigned short* __restrict__ Vx, unsigned short* __restrict__ CT){
  int z = blockIdx.z;
  const unsigned short* Xin = (z==3) ? XrT : XaT;
  const unsigned short* W   = Wb + z*(E_DIM*C_IN);
  const float* bias = (z==0)?bq:(z==1)?bk:(z==2)?bvb:bc;

  __shared__ unsigned short Als[128*64];
  __shared__ unsigned short Bls[64*64];
  int tid = threadIdx.x;
  int w = tid>>6, l = tid&63, g = l>>4, c16 = l&15;
  int wr = w>>1, wc = w&1;
  int s0 = blockIdx.x*128, e0 = blockIdx.y*64;

  f4v acc[4][2];
  #pragma unroll
  for(int m=0;m<4;m++)
    #pragma unroll
    for(int n=0;n<2;n++) acc[m][n] = (f4v){0.f,0.f,0.f,0.f};

  for(int kk=0;kk<4;kk++){
    __syncthreads();
    #pragma unroll
    for(int p=0;p<4;p++){
      int ck = p*256 + tid, row = ck>>3, ch = ck&7;
      s8v v = *(const s8v*)&Xin[(s0+row)*C_IN + kk*64 + ch*8];
      lds_wr8(Als, row, ch, v);
    }
    #pragma unroll
    for(int p=0;p<2;p++){
      int ck = p*256 + tid, row = ck>>3, ch = ck&7;
      s8v v = *(const s8v*)&W[(e0+row)*C_IN + kk*64 + ch*8];
      lds_wr8(Bls, row, ch, v);
    }
    __syncthreads();
    #pragma unroll
    for(int kb=0;kb<2;kb++){
      s8v bfr[2];
      #pragma unroll
      for(int n=0;n<2;n++) bfr[n] = lds_rd8(Bls, wc*32 + n*16 + c16, g + kb*4);
      #pragma unroll
      for(int m=0;m<4;m++){
        s8v af = lds_rd8(Als, wr*64 + m*16 + c16, g + kb*4);
        #pragma unroll
        for(int n=0;n<2;n++)
          acc[m][n] = __builtin_amdgcn_mfma_f32_16x16x32_bf16(af, bfr[n], acc[m][n], 0,0,0);
      }
    }
  }
  #pragma unroll
  for(int n=0;n<2;n++){
    int e = e0 + wc*32 + n*16 + c16;
    float bsv = bias[e];
    float cinv = 0.f, cbeta = 0.f;
    if(z==3){ cinv = cw[e]*rsqrtf(cvv[e]+EPSV); cbeta = cbb[e] - cm[e]*cinv; }
    #pragma unroll
    for(int m=0;m<4;m++){
      int sb = s0 + wr*64 + m*16 + g*4;
      if(z==2){
        s4v pk;
        #pragma unroll
        for(int i=0;i<4;i++) pk[i] = (short)f2bf(acc[m][n][i] + bsv);
        *(s4v*)&Vx[e*S_DIM + sb] = pk;
      } else {
        unsigned short* dst = (z==0)?QT:(z==1)?KT:CT;
        #pragma unroll
        for(int i=0;i<4;i++){
          float vv = acc[m][n][i] + bsv;
          if(z==3){ vv = vv*cinv + cbeta; vv = vv>0.f?vv:0.f; }
          dst[(sb+i)*E_DIM + e] = f2bf(vv);
        }
      }
    }
  }
}

// ---- flash attention (fixed-max softmax) + fuse -> fusedT (S,E) bf16 ----
// Block = 128 queries, 4 waves = (qh: 64-q group, kh: KV half). Each wave owns
// 64 q as 2 subgroups of 32 (qg). K/V frags read once, reused across qg.
// K tile: 16B swizzle; V tile: 8B swizzle (q4 ^ row&15) -> conflict-free b64.
// T14: next tile's global loads issued right after write-barrier.
__global__ __launch_bounds__(256,1) void k_attn(
    const unsigned short* __restrict__ QT, const unsigned short* __restrict__ KT,
    const unsigned short* __restrict__ Vx, const unsigned short* __restrict__ CT,
    const float* __restrict__ gamma, const float* __restrict__ temp,
    unsigned short* __restrict__ fusedT){
  __shared__ unsigned short SM[16384];  // K[kh0],K[kh1],V[kh0],V[kh1] tiles, 8KB each
  int tid = threadIdx.x;
  int w = tid>>6, l = tid&63, l31 = l&31, hi = l>>5;
  int qh = w&1, kh = w>>1;
  int fb = blockIdx.y*32 + blockIdx.x;
  int h = fb&7;                        // head-per-XCD remap
  int qb = (fb>>3)*128;
  float scl = 1.0f / temp[0];

  const unsigned short* Kb = SM + kh*4096;
  const unsigned short* Vb = SM + 8192 + kh*4096;

  // Q B-fragments (pre-scaled by 1/T): qf[qg][ks]
  s8v qf[2][4];
  #pragma unroll
  for(int qg=0;qg<2;qg++){
    int q = qb + qh*64 + qg*32 + l31;
    #pragma unroll
    for(int ks=0;ks<4;ks++){
      s8v r = *(const s8v*)&QT[q*E_DIM + h*HD + ks*16 + hi*8];
      #pragma unroll
      for(int j=0;j<8;j++) qf[qg][ks][j] = (short)f2bf(bf2f((unsigned short)r[j])*scl);
    }
  }

  f16v oacc[2][2];
  #pragma unroll
  for(int qg=0;qg<2;qg++)
    #pragma unroll
    for(int dt=0;dt<2;dt++)
      #pragma unroll
      for(int r=0;r<16;r++) oacc[qg][dt][r]=0.f;
  float lrun[2] = {0.f, 0.f};

  // staging decomposition (per thread): K: 4x16B, V: 4x16B
  int krow = tid>>2, kch2 = (tid&3)*2;          // K: 64 rows x 4 thr, 32B each
  int vrow = (tid&511)>>3, vch = tid&7;         // per 4KB tile: 64 rows x 8 thr

  s8v kreg[4], vreg[4];
  // prologue loads (t=0)
  #pragma unroll
  for(int p=0;p<2;p++){   // kp = p for K (thread covers both kh via p? no: 2 chunks per kh)
    #pragma unroll
    for(int kp=0;kp<1;kp++){}
  }
  // K: flats p*256+tid over 1024 chunks of 16B
  #pragma unroll
  for(int p=0;p<4;p++){
    int flat = p*256 + tid, kp = flat>>9, cid = flat&511, row = cid>>3, ch = cid&7;
    kreg[p] = *(const s8v*)&KT[((kp*32 + 0)*64 + row)*E_DIM + h*HD + ch*8];
  }
  #pragma unroll
  for(int p=0;p<4;p++){
    int flat = p*256 + tid, kp = flat>>9, cid = flat&511, row = cid>>3, ch = cid&7;
    vreg[p] = *(const s8v*)&Vx[(h*HD + row)*S_DIM + (kp*32 + 0)*64 + ch*8];
  }

  for(int t=0;t<32;t++){
    __syncthreads();
    // write staged regs to LDS
    #pragma unroll
    for(int p=0;p<4;p++){
      int flat = p*256 + tid, kp = flat>>9, cid = flat&511, row = cid>>3, ch = cid&7;
      lds_wr8((unsigned short*)SM + kp*4096, row, ch, kreg[p]);
    }
    #pragma unroll
    for(int p=0;p<4;p++){
      int flat = p*256 + tid, kp = flat>>9, cid = flat&511, row = cid>>3, ch = cid&7;
      union{ s8v v; s4v h2[2]; } u; u.v = vreg[p];
      unsigned short* Vt = (unsigned short*)SM + 8192 + kp*4096;
      lds_wr4q(Vt, row, ch*2,   u.h2[0]);
      lds_wr4q(Vt, row, ch*2+1, u.h2[1]);
    }
    __syncthreads();
    // prefetch t+1
    if(t < 31){
      #pragma unroll
      for(int p=0;p<4;p++){
        int flat = p*256 + tid, kp = flat>>9, cid = flat&511, row = cid>>3, ch = cid&7;
        kreg[p] = *(const s8v*)&KT[((kp*32 + t+1)*64 + row)*E_DIM + h*HD + ch*8];
      }
      #pragma unroll
      for(int p=0;p<4;p++){
        int flat = p*256 + tid, kp = flat>>9, cid = flat&511, row = cid>>3, ch = cid&7;
        vreg[p] = *(const s8v*)&Vx[(h*HD + row)*S_DIM + (kp*32 + t+1)*64 + ch*8];
      }
    }

    #pragma unroll
    for(int sub=0;sub<2;sub++){
      int kr = sub*32 + l31;
      s8v kf[4];
      #pragma unroll
      for(int ks=0;ks<4;ks++) kf[ks] = lds_rd8(Kb, kr, ks*2 + hi);

      union{ s8v v; unsigned u[4]; } pa[2][2];
      #pragma unroll
      for(int qg=0;qg<2;qg++){
        f16v d;
        #pragma unroll
        for(int r=0;r<16;r++) d[r]=0.f;
        #pragma unroll
        for(int ks=0;ks<4;ks++)
          d = __builtin_amdgcn_mfma_f32_32x32x16_bf16(kf[ks], qf[qg][ks], d, 0,0,0);
        float e[16], ls = 0.f;
        #pragma unroll
        for(int r=0;r<16;r++){ e[r] = __expf(d[r]); ls += e[r]; }
        lrun[qg] += ls;
        #pragma unroll
        for(int j=0;j<4;j++){
          pa[qg][0].u[j] = cvtpk_bf16(e[2*j],   e[2*j+1]);
          pa[qg][1].u[j] = cvtpk_bf16(e[8+2*j], e[8+2*j+1]);
        }
      }
      #pragma unroll
      for(int dt=0;dt<2;dt++){
        int vr = dt*32 + l31;
        union{ s8v v; s4v h2[2]; } vf;
        vf.h2[0] = lds_rd4q(Vb, vr, sub*8 + hi);
        vf.h2[1] = lds_rd4q(Vb, vr, sub*8 + 2 + hi);
        oacc[0][dt] = __builtin_amdgcn_mfma_f32_32x32x16_bf16(pa[0][0].v, vf.v, oacc[0][dt], 0,0,0);
        oacc[1][dt] = __builtin_amdgcn_mfma_f32_32x32x16_bf16(pa[1][0].v, vf.v, oacc[1][dt], 0,0,0);
        vf.h2[0] = lds_rd4q(Vb, vr, sub*8 + 4 + hi);
        vf.h2[1] = lds_rd4q(Vb, vr, sub*8 + 6 + hi);
        oacc[0][dt] = __builtin_amdgcn_mfma_f32_32x32x16_bf16(pa[0][1].v, vf.v, oacc[0][dt], 0,0,0);
        oacc[1][dt] = __builtin_amdgcn_mfma_f32_32x32x16_bf16(pa[1][1].v, vf.v, oacc[1][dt], 0,0,0);
      }
    }
  }

  #pragma unroll
  for(int qg=0;qg<2;qg++) lrun[qg] += __shfl_xor(lrun[qg], 32);

  // merge across kh, one qg phase at a time (reuse tile LDS)
  float* mb = (float*)SM;              // [2 qh][64 lanes][33 f32] = 16.9KB
  float* l_buf = mb + 4224;            // 64 f32
  float ga = gamma[0];
  #pragma unroll
  for(int qg=0;qg<2;qg++){
    __syncthreads();
    if(kh==1){
      float* dst = mb + (qh*64 + l)*33;
      #pragma unroll
      for(int r=0;r<16;r++){ dst[r] = oacc[qg][0][r]; dst[16+r] = oacc[qg][1][r]; }
      dst[32] = lrun[qg];
    }
    __syncthreads();
    float ltot = 0.f;
    if(kh==0){
      const float* src = mb + (qh*64 + l)*33;
      #pragma unroll
      for(int r=0;r<16;r++){ oacc[qg][0][r] += src[r]; oacc[qg][1][r] += src[16+r]; }
      ltot = lrun[qg] + src[32];
      if(hi==0) l_buf[qh*32 + l31] = ltot;
    }
    __syncthreads();
    if(kh==0){
      #pragma unroll
      for(int dt=0;dt<2;dt++){
        int e = h*HD + dt*32 + l31;
        #pragma unroll
        for(int g4=0;g4<4;g4++){
          float4 lv = *(float4*)&l_buf[qh*32 + g4*8 + hi*4];
          float la[4] = {lv.x, lv.y, lv.z, lv.w};
          #pragma unroll
          for(int j=0;j<4;j++){
            int r = g4*4 + j;
            int qrow = qb + qh*64 + qg*32 + j + g4*8 + hi*4;
            float o = oacc[qg][dt][r]/la[j]*ga + bf2f(CT[qrow*E_DIM + e]);
            fusedT[qrow*E_DIM + e] = f2bf(o);
          }
        }
      }
    }
  }
}

// ---- final: out(c,s) = gelu(rbn(rs_w . fused + rs_b)) fp32, 64x64 tiles ----
__global__ __launch_bounds__(256) void k_final(
    const unsigned short* __restrict__ Wrs,
    const unsigned short* __restrict__ fusedT,
    const float* __restrict__ rsb,
    const float* __restrict__ rw, const float* __restrict__ rbb,
    const float* __restrict__ rm, const float* __restrict__ rv,
    float* __restrict__ out){
  __shared__ unsigned short Als[64*64];
  __shared__ unsigned short Bls[64*64];
  int tid = threadIdx.x;
  int w = tid>>6, l = tid&63, g = l>>4, c16 = l&15;
  int wr2 = w>>1, wc2 = w&1;
  int sB0 = blockIdx.x*64, c0 = blockIdx.y*64;
  f4v acc[2][2];
  #pragma unroll
  for(int m=0;m<2;m++)
    #pragma unroll
    for(int n=0;n<2;n++) acc[m][n]=(f4v){0.f,0.f,0.f,0.f};
  for(int kk=0;kk<8;kk++){
    __syncthreads();
    #pragma unroll
    for(int p=0;p<2;p++){
      int ck = p*256+tid, row=ck>>3, ch=ck&7;
      s8v v = *(const s8v*)&Wrs[(c0+row)*E_DIM + kk*64 + ch*8];
      lds_wr8(Als, row, ch, v);
    }
    #pragma unroll
    for(int p=0;p<2;p++){
      int ck = p*256+tid, row=ck>>3, ch=ck&7;
      s8v v = *(const s8v*)&fusedT[(sB0+row)*E_DIM + kk*64 + ch*8];
      lds_wr8(Bls, row, ch, v);
    }
    __syncthreads();
    #pragma unroll
    for(int kb=0;kb<2;kb++){
      s8v af[2]; s8v bfr[2];
      #pragma unroll
      for(int m=0;m<2;m++) af[m] = lds_rd8(Als, wr2*32 + m*16 + c16, g + kb*4);
      #pragma unroll
      for(int n=0;n<2;n++) bfr[n] = lds_rd8(Bls, wc2*32 + n*16 + c16, g + kb*4);
      #pragma unroll
      for(int m=0;m<2;m++)
        #pragma unroll
        for(int n=0;n<2;n++)
          acc[m][n] = __builtin_amdgcn_mfma_f32_16x16x32_bf16(af[m], bfr[n], acc[m][n],0,0,0);
    }
  }
  #pragma unroll
  for(int m=0;m<2;m++){
    #pragma unroll
    for(int i=0;i<4;i++){
      int c = c0 + wr2*32 + m*16 + g*4 + i;
      float bias = rsb[c];
      float rinv = rw[c]*rsqrtf(rv[c]+EPSV);
      float rbeta = rbb[c] - rm[c]*rinv;
      #pragma unroll
      for(int n=0;n<2;n++){
        int s = sB0 + wc2*32 + n*16 + c16;
        float vv = acc[m][n][i] + bias;
        vv = vv*rinv + rbeta;
        out[c*S_DIM + s] = 0.5f*vv*(1.0f + erff(vv*0.70710678118f));
      }
    }
  }
}

extern "C" void kernel_launch(void* const* d_in, const int* in_sizes, int n_in,
                              void* d_out, int out_size, void* d_ws, size_t ws_size,
                              hipStream_t stream){
  const float* x     = (const float*)d_in[0];
  const float* bn1w  = (const float*)d_in[1];
  const float* bn1b  = (const float*)d_in[2];
  const float* bn1m  = (const float*)d_in[3];
  const float* bn1v  = (const float*)d_in[4];
  const float* Wq    = (const float*)d_in[5];
  const float* bq    = (const float*)d_in[6];
  const float* Wk    = (const float*)d_in[7];
  const float* bk    = (const float*)d_in[8];
  const float* Wv    = (const float*)d_in[9];
  const float* bv    = (const float*)d_in[10];
  const float* gamma = (const float*)d_in[11];
  const float* temp  = (const float*)d_in[12];
  const float* convw = (const float*)d_in[13];
  const float* convb = (const float*)d_in[14];
  const float* cbnw  = (const float*)d_in[15];
  const float* cbnb  = (const float*)d_in[16];
  const float* cbnm  = (const float*)d_in[17];
  const float* cbnv  = (const float*)d_in[18];
  const float* rsw   = (const float*)d_in[19];
  const float* rsbp  = (const float*)d_in[20];
  const float* rbnw  = (const float*)d_in[21];
  const float* rbnb  = (const float*)d_in[22];
  const float* rbnm  = (const float*)d_in[23];
  const float* rbnv  = (const float*)d_in[24];
  float* out = (float*)d_out;

  unsigned short* ws  = (unsigned short*)d_ws;
  unsigned short* XaT = ws;                          // (S,C) bf16
  unsigned short* XrT = XaT + S_DIM*C_IN;            // (S,C) bf16
  unsigned short* Wb  = XrT + S_DIM*C_IN;            // q,k,v,conv weights bf16
  unsigned short* Wrs = Wb + 4*E_DIM*C_IN;           // rs weight bf16 (256x512)
  unsigned short* QT  = Wrs + C_IN*E_DIM;            // (S,E)
  unsigned short* KT  = QT + S_DIM*E_DIM;            // (S,E)
  unsigned short* Vx  = KT + S_DIM*E_DIM;            // (E,S)
  unsigned short* CT  = Vx + S_DIM*E_DIM;            // (S,E) conv path
  unsigned short* fusedT = CT + S_DIM*E_DIM;         // (S,E)

  k_wcvt<<<dim3(512,5),256,0,stream>>>(Wq, Wk, Wv, convw, rsw, Wb);
  k_prep<<<dim3(128,8),256,0,stream>>>(x, bn1w, bn1b, bn1m, bn1v, XaT, XrT);
  k_proj<<<dim3(32,8,4),256,0,stream>>>(XaT, XrT, Wb, bq, bk, bv, convb,
                                        cbnw, cbnb, cbnm, cbnv, QT, KT, Vx, CT);
  k_attn<<<dim3(32,8),256,0,stream>>>(QT, KT, Vx, CT, gamma, temp, fusedT);
  k_final<<<dim3(64,4),256,0,stream>>>(Wrs, fusedT, rsbp, rbnw, rbnb, rbnm, rbnv, out);
}

// Round 5
// 87.958 us; speedup vs baseline: 2.0110x; 1.0716x over previous
//
#include <hip/hip_runtime.h>

#define S_DIM 4096
#define C_IN  256
#define E_DIM 512
#define HD    64
#define EPSV  1e-5f

typedef __attribute__((ext_vector_type(8))) short s8v;
typedef __attribute__((ext_vector_type(4))) short s4v;
typedef __attribute__((ext_vector_type(4))) float f4v;
typedef __attribute__((ext_vector_type(16))) float f16v;

__device__ __forceinline__ float bf2f(unsigned short h){
  union{unsigned u; float f;} v; v.u = ((unsigned)h)<<16; return v.f;
}
__device__ __forceinline__ unsigned short f2bf(float f){
  union{float f; unsigned u;} v; v.f = f;
  unsigned r = v.u + 0x7fffu + ((v.u>>16)&1u);   // RNE
  return (unsigned short)(r>>16);
}
__device__ __forceinline__ unsigned cvtpk_bf16(float lo, float hi_){
  unsigned r;
  asm("v_cvt_pk_bf16_f32 %0, %1, %2" : "=v"(r) : "v"(lo), "v"(hi_));
  return r;
}
// 16B-chunk XOR swizzle read (rows of 64 bf16) — content pre-swizzled in global
__device__ __forceinline__ s8v lds_rd8(const unsigned short* b, int row, int ck){
  return *(const s8v*)&b[(row<<6) + (((ck)^(row&7))<<3)];
}
__device__ __forceinline__ void lds_wr8(unsigned short* b, int row, int ck, s8v v){
  *(s8v*)&b[(row<<6) + (((ck)^(row&7))<<3)] = v;
}
// 8B-granule XOR swizzle read for V tiles
__device__ __forceinline__ s4v lds_rd4q(const unsigned short* b, int row, int q4){
  return *(const s4v*)&b[(row<<6) + (((q4)^(row&15))<<2)];
}
// async global->LDS, 16B per lane, LDS dest wave-uniform base
__device__ __forceinline__ void gl_lds16(const unsigned short* g, unsigned short* l){
  __builtin_amdgcn_global_load_lds(
      (const __attribute__((address_space(1))) unsigned int*)g,
      (__attribute__((address_space(3))) unsigned int*)l, 16, 0, 0);
}

// ---- convert 5 weight matrices fp32 -> bf16 into ws ----
__global__ __launch_bounds__(256) void k_wcvt(const float* __restrict__ w0,
    const float* __restrict__ w1, const float* __restrict__ w2,
    const float* __restrict__ w3, const float* __restrict__ w4,
    unsigned short* __restrict__ dst){
  int i = blockIdx.x*256 + threadIdx.x;
  int z = blockIdx.y;
  const float* s = (z==0)?w0:(z==1)?w1:(z==2)?w2:(z==3)?w3:w4;
  dst[z*(E_DIM*C_IN) + i] = f2bf(s[i]);
}

// ---- x (C,S) fp32 -> XaT (S,C) bf16 [relu(bn1)] and XrT (S,C) bf16 [raw] ----
__global__ __launch_bounds__(256) void k_prep(const float* __restrict__ x,
    const float* __restrict__ bw, const float* __restrict__ bb,
    const float* __restrict__ bm, const float* __restrict__ bvar,
    unsigned short* __restrict__ XaT, unsigned short* __restrict__ XrT){
  __shared__ float tile[32][33];
  int tid = threadIdx.x;
  int tx = tid & 31, ty = tid >> 5;
  int s0 = blockIdx.x*32, c0 = blockIdx.y*32;
  #pragma unroll
  for(int p=0;p<4;p++){
    int c = c0 + ty + p*8;
    tile[ty+p*8][tx] = x[c*S_DIM + s0 + tx];
  }
  __syncthreads();
  int cc = c0 + tx;
  float inv  = bw[cc] * rsqrtf(bvar[cc] + EPSV);
  float beta = bb[cc] - bm[cc]*inv;
  #pragma unroll
  for(int p=0;p<4;p++){
    int s = s0 + ty + p*8;
    float v = tile[tx][ty+p*8];
    float a = v*inv + beta; a = a>0.f?a:0.f;
    XaT[s*C_IN + cc] = f2bf(a);
    XrT[s*C_IN + cc] = f2bf(v);
  }
}

// ---- uniform projection GEMM ----
// z=0 Q ->(S,E), z=1 K ->(S,E) chunk-swizzled, z=2 V ->(E,S) granule-swizzled,
// z=3 conv(+cbn+relu) ->(S,E)
__global__ __launch_bounds__(256) void k_proj(
    const unsigned short* __restrict__ XaT, const unsigned short* __restrict__ XrT,
    const unsigned short* __restrict__ Wb,
    const float* __restrict__ bq, const float* __restrict__ bk,
    const float* __restrict__ bvb, const float* __restrict__ bc,
    const float* __restrict__ cw, const float* __restrict__ cbb,
    const float* __restrict__ cm, const float* __restrict__ cvv,
    unsigned short* __restrict__ QT, unsigned short* __restrict__ KT,
    unsigned short* __restrict__ Vx, unsigned short* __restrict__ CT){
  int z = blockIdx.z;
  const unsigned short* Xin = (z==3) ? XrT : XaT;
  const unsigned short* W   = Wb + z*(E_DIM*C_IN);
  const float* bias = (z==0)?bq:(z==1)?bk:(z==2)?bvb:bc;

  __shared__ unsigned short Als[128*64];
  __shared__ unsigned short Bls[64*64];
  int tid = threadIdx.x;
  int w = tid>>6, l = tid&63, g = l>>4, c16 = l&15;
  int wr = w>>1, wc = w&1;
  int s0 = blockIdx.x*128, e0 = blockIdx.y*64;

  f4v acc[4][2];
  #pragma unroll
  for(int m=0;m<4;m++)
    #pragma unroll
    for(int n=0;n<2;n++) acc[m][n] = (f4v){0.f,0.f,0.f,0.f};

  for(int kk=0;kk<4;kk++){
    __syncthreads();
    #pragma unroll
    for(int p=0;p<4;p++){
      int ck = p*256 + tid, row = ck>>3, ch = ck&7;
      s8v v = *(const s8v*)&Xin[(s0+row)*C_IN + kk*64 + ch*8];
      lds_wr8(Als, row, ch, v);
    }
    #pragma unroll
    for(int p=0;p<2;p++){
      int ck = p*256 + tid, row = ck>>3, ch = ck&7;
      s8v v = *(const s8v*)&W[(e0+row)*C_IN + kk*64 + ch*8];
      lds_wr8(Bls, row, ch, v);
    }
    __syncthreads();
    #pragma unroll
    for(int kb=0;kb<2;kb++){
      s8v bfr[2];
      #pragma unroll
      for(int n=0;n<2;n++) bfr[n] = lds_rd8(Bls, wc*32 + n*16 + c16, g + kb*4);
      #pragma unroll
      for(int m=0;m<4;m++){
        s8v af = lds_rd8(Als, wr*64 + m*16 + c16, g + kb*4);
        #pragma unroll
        for(int n=0;n<2;n++)
          acc[m][n] = __builtin_amdgcn_mfma_f32_16x16x32_bf16(af, bfr[n], acc[m][n], 0,0,0);
      }
    }
  }
  #pragma unroll
  for(int n=0;n<2;n++){
    int e = e0 + wc*32 + n*16 + c16;
    float bsv = bias[e];
    float cinv = 0.f, cbeta = 0.f;
    if(z==3){ cinv = cw[e]*rsqrtf(cvv[e]+EPSV); cbeta = cbb[e] - cm[e]*cinv; }
    #pragma unroll
    for(int m=0;m<4;m++){
      int sb = s0 + wr*64 + m*16 + g*4;
      if(z==2){
        s4v pk;
        #pragma unroll
        for(int i=0;i<4;i++) pk[i] = (short)f2bf(acc[m][n][i] + bsv);
        // bake 8B-granule XOR swizzle into the key position (within 64-key tile)
        int sb2 = (sb & ~63) | ((((sb>>2)&15) ^ (e&15))<<2);
        *(s4v*)&Vx[e*S_DIM + sb2] = pk;
      } else {
        unsigned short* dst = (z==0)?QT:(z==1)?KT:CT;
        #pragma unroll
        for(int i=0;i<4;i++){
          float vv = acc[m][n][i] + bsv;
          if(z==3){ vv = vv*cinv + cbeta; vv = vv>0.f?vv:0.f; }
          int key = sb+i;
          int ee = e;
          if(z==1) ee = (e & ~56) | ((((e>>3)&7) ^ (key&7))<<3); // 16B-chunk swizzle
          dst[key*E_DIM + ee] = f2bf(vv);
        }
      }
    }
  }
}

// ---- flash attention (fixed-max softmax) + fuse -> fusedT (S,E) bf16 ----
// 512-thr blocks: 8 waves = (qh x2, kh x4); 128 q per block, grid 256 (1/CU).
// K/V staged via global_load_lds from pre-swizzled KT/Vx into linear LDS,
// double-buffered (2 x 64KB). l computed via MFMA against a ones-fragment.
__global__ __launch_bounds__(512,2) void k_attn(
    const unsigned short* __restrict__ QT, const unsigned short* __restrict__ KT,
    const unsigned short* __restrict__ Vx, const unsigned short* __restrict__ CT,
    const float* __restrict__ gamma, const float* __restrict__ temp,
    unsigned short* __restrict__ fusedT){
  __shared__ unsigned short SM[65536];   // 2 bufs x 8 tiles x 4096 elems = 128KB
  int tid = threadIdx.x;
  int w = tid>>6, l = tid&63, l31 = l&31, hi = l>>5;
  int qh = w>>2, kh = w&3;
  int bx = blockIdx.x;
  int h = bx&7;                           // head-per-XCD
  int q0b = (bx>>3)*128;
  float scl = 1.4426950408889634f / temp[0];   // log2(e)/T  -> exp2 path

  // Q B-fragments (pre-scaled): qf[qg][ks]
  s8v qf[2][4];
  #pragma unroll
  for(int qg=0;qg<2;qg++){
    int q = q0b + qh*64 + qg*32 + l31;
    #pragma unroll
    for(int ks=0;ks<4;ks++){
      s8v r = *(const s8v*)&QT[q*E_DIM + h*HD + ks*16 + hi*8];
      #pragma unroll
      for(int j=0;j<8;j++) qf[qg][ks][j] = (short)f2bf(bf2f((unsigned short)r[j])*scl);
    }
  }
  s8v ones;
  #pragma unroll
  for(int j=0;j<8;j++) ones[j] = (short)0x3F80;   // bf16 1.0

  f16v oacc[2][2];   // [qg][dt]
  f16v lacc[2];      // [qg] softmax denominators (same q-reg mapping as oacc)
  #pragma unroll
  for(int qg=0;qg<2;qg++){
    #pragma unroll
    for(int r=0;r<16;r++){ oacc[qg][0][r]=0.f; oacc[qg][1][r]=0.f; lacc[qg][r]=0.f; }
  }

  // ---- staging: 8 DMA instrs/thread; flat 16B-granule = (w*8+j)*64 + lane ----
  #define STAGE(BUF, T) { \
    _Pragma("unroll") \
    for(int j=0;j<8;j++){ \
      int flat = (w*8+j)*64 + l; \
      int tile = flat>>9, gg = flat&511, row = gg>>3, ch = gg&7; \
      int khp = tile&3; \
      int sK = khp*1024 + (T)*64; \
      const unsigned short* src = (tile<4) \
        ? &KT[(sK+row)*E_DIM + h*HD + ch*8] \
        : &Vx[(h*HD+row)*S_DIM + sK + ch*8]; \
      gl_lds16(src, SM + (BUF)*32768 + (w*8+j)*512); \
    } }

  int buf = 0;
  STAGE(0, 0);
  for(int t=0;t<16;t++){
    asm volatile("s_waitcnt vmcnt(0)" ::: "memory");
    __syncthreads();
    if(t<15) STAGE(buf^1, t+1);
    const unsigned short* Kb = SM + buf*32768 + kh*4096;
    const unsigned short* Vb = SM + buf*32768 + (4+kh)*4096;

    #pragma unroll
    for(int sub=0;sub<2;sub++){
      int kr = sub*32 + l31;
      s8v kf[4];
      #pragma unroll
      for(int ks=0;ks<4;ks++) kf[ks] = lds_rd8(Kb, kr, ks*2 + hi);

      union{ s8v v; unsigned u[4]; } pa[2][2];
      #pragma unroll
      for(int qg=0;qg<2;qg++){
        f16v d;
        #pragma unroll
        for(int r=0;r<16;r++) d[r]=0.f;
        #pragma unroll
        for(int ks=0;ks<4;ks++)
          d = __builtin_amdgcn_mfma_f32_32x32x16_bf16(kf[ks], qf[qg][ks], d, 0,0,0);
        float e_[16];
        #pragma unroll
        for(int r=0;r<16;r++) e_[r] = __builtin_amdgcn_exp2f(d[r]);
        #pragma unroll
        for(int j=0;j<4;j++){
          pa[qg][0].u[j] = cvtpk_bf16(e_[2*j],   e_[2*j+1]);
          pa[qg][1].u[j] = cvtpk_bf16(e_[8+2*j], e_[8+2*j+1]);
        }
        lacc[qg] = __builtin_amdgcn_mfma_f32_32x32x16_bf16(pa[qg][0].v, ones, lacc[qg],0,0,0);
        lacc[qg] = __builtin_amdgcn_mfma_f32_32x32x16_bf16(pa[qg][1].v, ones, lacc[qg],0,0,0);
      }
      #pragma unroll
      for(int dt=0;dt<2;dt++){
        int vr = dt*32 + l31;
        union{ s8v v; s4v h2[2]; } vf;
        vf.h2[0] = lds_rd4q(Vb, vr, sub*8 + hi);
        vf.h2[1] = lds_rd4q(Vb, vr, sub*8 + 2 + hi);
        oacc[0][dt] = __builtin_amdgcn_mfma_f32_32x32x16_bf16(pa[0][0].v, vf.v, oacc[0][dt], 0,0,0);
        oacc[1][dt] = __builtin_amdgcn_mfma_f32_32x32x16_bf16(pa[1][0].v, vf.v, oacc[1][dt], 0,0,0);
        vf.h2[0] = lds_rd4q(Vb, vr, sub*8 + 4 + hi);
        vf.h2[1] = lds_rd4q(Vb, vr, sub*8 + 6 + hi);
        oacc[0][dt] = __builtin_amdgcn_mfma_f32_32x32x16_bf16(pa[0][1].v, vf.v, oacc[0][dt], 0,0,0);
        oacc[1][dt] = __builtin_amdgcn_mfma_f32_32x32x16_bf16(pa[1][1].v, vf.v, oacc[1][dt], 0,0,0);
      }
    }
    buf ^= 1;
  }

  // ---- merge 4 kh-waves per qh group; additive (shared fixed max) ----
  float* slab = (float*)SM;   // [qh][src(3)][64 lanes][48] = 73,728 B
  float ga = gamma[0];
  #pragma unroll
  for(int qg=0;qg<2;qg++){
    __syncthreads();
    if(kh!=0){
      float* dst = slab + ((qh*3 + (kh-1))*64 + l)*48;
      #pragma unroll
      for(int r=0;r<16;r++){
        dst[r] = oacc[qg][0][r]; dst[16+r] = oacc[qg][1][r]; dst[32+r] = lacc[qg][r];
      }
    }
    __syncthreads();
    if(kh==0){
      f16v o0 = oacc[qg][0], o1 = oacc[qg][1], lt = lacc[qg];
      #pragma unroll
      for(int s=0;s<3;s++){
        const float* src = slab + ((qh*3 + s)*64 + l)*48;
        #pragma unroll
        for(int r=0;r<16;r++){ o0[r] += src[r]; o1[r] += src[16+r]; lt[r] += src[32+r]; }
      }
      #pragma unroll
      for(int r=0;r<16;r++){
        int qrow = q0b + qh*64 + qg*32 + (r&3) + 8*(r>>2) + 4*hi;
        float rl = __builtin_amdgcn_rcpf(lt[r]) * ga;
        int e0i = h*HD + l31;
        float oA = o0[r]*rl + bf2f(CT[qrow*E_DIM + e0i]);
        float oB = o1[r]*rl + bf2f(CT[qrow*E_DIM + e0i + 32]);
        fusedT[qrow*E_DIM + e0i]      = f2bf(oA);
        fusedT[qrow*E_DIM + e0i + 32] = f2bf(oB);
      }
    }
  }
  #undef STAGE
}

// ---- final: out(c,s) = gelu(rbn(rs_w . fused + rs_b)) fp32, 64x64 tiles ----
__global__ __launch_bounds__(256) void k_final(
    const unsigned short* __restrict__ Wrs,
    const unsigned short* __restrict__ fusedT,
    const float* __restrict__ rsb,
    const float* __restrict__ rw, const float* __restrict__ rbb,
    const float* __restrict__ rm, const float* __restrict__ rv,
    float* __restrict__ out){
  __shared__ unsigned short Als[64*64];
  __shared__ unsigned short Bls[64*64];
  int tid = threadIdx.x;
  int w = tid>>6, l = tid&63, g = l>>4, c16 = l&15;
  int wr2 = w>>1, wc2 = w&1;
  int sB0 = blockIdx.x*64, c0 = blockIdx.y*64;
  f4v acc[2][2];
  #pragma unroll
  for(int m=0;m<2;m++)
    #pragma unroll
    for(int n=0;n<2;n++) acc[m][n]=(f4v){0.f,0.f,0.f,0.f};
  for(int kk=0;kk<8;kk++){
    __syncthreads();
    #pragma unroll
    for(int p=0;p<2;p++){
      int ck = p*256+tid, row=ck>>3, ch=ck&7;
      s8v v = *(const s8v*)&Wrs[(c0+row)*E_DIM + kk*64 + ch*8];
      lds_wr8(Als, row, ch, v);
    }
    #pragma unroll
    for(int p=0;p<2;p++){
      int ck = p*256+tid, row=ck>>3, ch=ck&7;
      s8v v = *(const s8v*)&fusedT[(sB0+row)*E_DIM + kk*64 + ch*8];
      lds_wr8(Bls, row, ch, v);
    }
    __syncthreads();
    #pragma unroll
    for(int kb=0;kb<2;kb++){
      s8v af[2]; s8v bfr[2];
      #pragma unroll
      for(int m=0;m<2;m++) af[m] = lds_rd8(Als, wr2*32 + m*16 + c16, g + kb*4);
      #pragma unroll
      for(int n=0;n<2;n++) bfr[n] = lds_rd8(Bls, wc2*32 + n*16 + c16, g + kb*4);
      #pragma unroll
      for(int m=0;m<2;m++)
        #pragma unroll
        for(int n=0;n<2;n++)
          acc[m][n] = __builtin_amdgcn_mfma_f32_16x16x32_bf16(af[m], bfr[n], acc[m][n],0,0,0);
    }
  }
  #pragma unroll
  for(int m=0;m<2;m++){
    #pragma unroll
    for(int i=0;i<4;i++){
      int c = c0 + wr2*32 + m*16 + g*4 + i;
      float bias = rsb[c];
      float rinv = rw[c]*rsqrtf(rv[c]+EPSV);
      float rbeta = rbb[c] - rm[c]*rinv;
      #pragma unroll
      for(int n=0;n<2;n++){
        int s = sB0 + wc2*32 + n*16 + c16;
        float vv = acc[m][n][i] + bias;
        vv = vv*rinv + rbeta;
        out[c*S_DIM + s] = 0.5f*vv*(1.0f + erff(vv*0.70710678118f));
      }
    }
  }
}

extern "C" void kernel_launch(void* const* d_in, const int* in_sizes, int n_in,
                              void* d_out, int out_size, void* d_ws, size_t ws_size,
                              hipStream_t stream){
  const float* x     = (const float*)d_in[0];
  const float* bn1w  = (const float*)d_in[1];
  const float* bn1b  = (const float*)d_in[2];
  const float* bn1m  = (const float*)d_in[3];
  const float* bn1v  = (const float*)d_in[4];
  const float* Wq    = (const float*)d_in[5];
  const float* bq    = (const float*)d_in[6];
  const float* Wk    = (const float*)d_in[7];
  const float* bk    = (const float*)d_in[8];
  const float* Wv    = (const float*)d_in[9];
  const float* bv    = (const float*)d_in[10];
  const float* gamma = (const float*)d_in[11];
  const float* temp  = (const float*)d_in[12];
  const float* convw = (const float*)d_in[13];
  const float* convb = (const float*)d_in[14];
  const float* cbnw  = (const float*)d_in[15];
  const float* cbnb  = (const float*)d_in[16];
  const float* cbnm  = (const float*)d_in[17];
  const float* cbnv  = (const float*)d_in[18];
  const float* rsw   = (const float*)d_in[19];
  const float* rsbp  = (const float*)d_in[20];
  const float* rbnw  = (const float*)d_in[21];
  const float* rbnb  = (const float*)d_in[22];
  const float* rbnm  = (const float*)d_in[23];
  const float* rbnv  = (const float*)d_in[24];
  float* out = (float*)d_out;

  unsigned short* ws  = (unsigned short*)d_ws;
  unsigned short* XaT = ws;                          // (S,C) bf16
  unsigned short* XrT = XaT + S_DIM*C_IN;            // (S,C) bf16
  unsigned short* Wb  = XrT + S_DIM*C_IN;            // q,k,v,conv weights bf16
  unsigned short* Wrs = Wb + 4*E_DIM*C_IN;           // rs weight bf16 (256x512)
  unsigned short* QT  = Wrs + C_IN*E_DIM;            // (S,E)
  unsigned short* KT  = QT + S_DIM*E_DIM;            // (S,E) chunk-swizzled
  unsigned short* Vx  = KT + S_DIM*E_DIM;            // (E,S) granule-swizzled
  unsigned short* CT  = Vx + S_DIM*E_DIM;            // (S,E) conv path
  unsigned short* fusedT = CT + S_DIM*E_DIM;         // (S,E)

  k_wcvt<<<dim3(512,5),256,0,stream>>>(Wq, Wk, Wv, convw, rsw, Wb);
  k_prep<<<dim3(128,8),256,0,stream>>>(x, bn1w, bn1b, bn1m, bn1v, XaT, XrT);
  k_proj<<<dim3(32,8,4),256,0,stream>>>(XaT, XrT, Wb, bq, bk, bv, convb,
                                        cbnw, cbnb, cbnm, cbnv, QT, KT, Vx, CT);
  k_attn<<<dim3(256),512,0,stream>>>(QT, KT, Vx, CT, gamma, temp, fusedT);
  k_final<<<dim3(64,4),256,0,stream>>>(Wrs, fusedT, rsbp, rbnw, rbnb, rbnm, rbnv, out);
}